// Round 12
// baseline (326.042 us; speedup 1.0000x reference)
//
#include <hip/hip_runtime.h>
#include <stdint.h>

#define DDIM 1024
#define HDIM 2048
#define EEXP 8
#define TTOK 4096   // B*S
#define CAP  4096   // max tokens per expert
#define GBLK 32     // tokens per gating block

using f32x4 = __attribute__((ext_vector_type(4))) float;
using bfrag = __attribute__((ext_vector_type(8))) short;   // 8 bf16 (4 VGPRs)

__device__ __forceinline__ unsigned short f2bf(float f) {
  unsigned u = __builtin_bit_cast(unsigned, f);
  return (unsigned short)((u + 0x7fffu + ((u >> 16) & 1u)) >> 16);  // RNE
}

// pack 8 fp32 -> 8 bf16 (round-to-nearest)
__device__ __forceinline__ uint4 pack8(float4 a, float4 b) {
  auto p2 = [](float lo, float hi) {
    unsigned ulo = __builtin_bit_cast(unsigned, lo);
    unsigned uhi = __builtin_bit_cast(unsigned, hi);
    return ((ulo + 0x8000u) >> 16) | ((uhi + 0x8000u) & 0xffff0000u);
  };
  return uint4{p2(a.x, a.y), p2(a.z, a.w), p2(b.x, b.y), p2(b.z, b.w)};
}

__device__ __forceinline__ void gl16(const void* g, void* l) {
  __builtin_amdgcn_global_load_lds(
      (const __attribute__((address_space(1))) unsigned int*)g,
      (__attribute__((address_space(3))) unsigned int*)l, 16, 0, 0);
}

// ---------------- fp32 -> bf16 conversion (x, W1, W2) ----------------
__global__ void cvt_kernel(const float4* __restrict__ src, ushort4* __restrict__ dst, int n4) {
  int i = blockIdx.x * blockDim.x + threadIdx.x;
  int st = gridDim.x * blockDim.x;
  for (; i < n4; i += st) {
    float4 v = src[i];
    ushort4 o;
    o.x = f2bf(v.x); o.y = f2bf(v.y); o.z = f2bf(v.z); o.w = f2bf(v.w);
    dst[i] = o;
  }
}

// ---------------- gating: block-local aggregation (r10-verified) ----------------
__global__ __launch_bounds__(256) void gating_kernel(
    const float* __restrict__ x, const float* __restrict__ Wg,
    int* __restrict__ cnt,      // padded: cnt[e*16]
    float* __restrict__ imp,    // padded: imp[e*16]
    float* __restrict__ entacc,
    int* __restrict__ slots, float* __restrict__ wlist)
{
  __shared__ float sWg[EEXP * DDIM];     // 32 KB
  __shared__ float sImp[EEXP];
  __shared__ float sEnt;
  __shared__ int   sCnt[EEXP];
  __shared__ int   sBase[EEXP];
  __shared__ int   sSlot[EEXP][GBLK];
  __shared__ float sWt[EEXP][GBLK];

  const int tid = threadIdx.x;
  for (int i = tid; i < EEXP * DDIM / 4; i += 256)
    ((float4*)sWg)[i] = ((const float4*)Wg)[i];
  if (tid < EEXP) { sImp[tid] = 0.f; sCnt[tid] = 0; }
  if (tid == EEXP) sEnt = 0.f;
  __syncthreads();

  const int wv = tid >> 6, lane = tid & 63;
  float impAcc[EEXP];
#pragma unroll
  for (int e = 0; e < EEXP; ++e) impAcc[e] = 0.f;
  float entAcc = 0.f;

  for (int it = 0; it < GBLK / 4; ++it) {          // 8 tokens per wave
    const int t = blockIdx.x * GBLK + wv * (GBLK / 4) + it;
    const float4* xt4 = (const float4*)(x + (size_t)t * DDIM);
    float s[EEXP];
#pragma unroll
    for (int e = 0; e < EEXP; ++e) s[e] = 0.f;
#pragma unroll
    for (int i = 0; i < DDIM / 256; ++i) {
      float4 xv = xt4[i * 64 + lane];
#pragma unroll
      for (int e = 0; e < EEXP; ++e) {
        float4 w4 = ((const float4*)sWg)[e * (DDIM / 4) + i * 64 + lane];
        s[e] += xv.x * w4.x + xv.y * w4.y + xv.z * w4.z + xv.w * w4.w;
      }
    }
#pragma unroll
    for (int off = 32; off > 0; off >>= 1) {
#pragma unroll
      for (int e = 0; e < EEXP; ++e) s[e] += __shfl_xor(s[e], off);
    }
    if (lane == 0) {
      float m = s[0];
#pragma unroll
      for (int e = 1; e < EEXP; ++e) m = fmaxf(m, s[e]);
      float ex[EEXP], sum = 0.f;
#pragma unroll
      for (int e = 0; e < EEXP; ++e) { ex[e] = __expf(s[e] - m); sum += ex[e]; }
      float inv = 1.f / sum;
#pragma unroll
      for (int e = 0; e < EEXP; ++e) {
        float p = ex[e] * inv;
        impAcc[e] += p;
        entAcc += p * __logf(fmaxf(p, 1e-9f));
      }
      // top-2, strict > keeps lowest index on ties (matches jax.lax.top_k)
      int e0 = 0;
#pragma unroll
      for (int e = 1; e < EEXP; ++e) if (s[e] > s[e0]) e0 = e;
      int e1 = (e0 == 0) ? 1 : 0;
#pragma unroll
      for (int e = 0; e < EEXP; ++e) if (e != e0 && s[e] > s[e1]) e1 = e;
      float tt = __expf(s[e1] - s[e0]);
      float p0 = 1.f / (1.f + tt);
      float p1 = tt / (1.f + tt);
      int pos0 = atomicAdd(&sCnt[e0], 1);
      sSlot[e0][pos0] = t * 2;     sWt[e0][pos0] = p0;
      int pos1 = atomicAdd(&sCnt[e1], 1);
      sSlot[e1][pos1] = t * 2 + 1; sWt[e1][pos1] = p1;
    }
  }
  if (lane == 0) {
#pragma unroll
    for (int e = 0; e < EEXP; ++e) atomicAdd(&sImp[e], impAcc[e]);
    atomicAdd(&sEnt, entAcc);
  }
  __syncthreads();
  if (tid < EEXP) {
    sBase[tid] = atomicAdd(&cnt[tid << 4], sCnt[tid]);   // padded line per expert
    atomicAdd(&imp[tid << 4], sImp[tid]);
  }
  if (tid == EEXP) atomicAdd(entacc, sEnt);
  __syncthreads();
#pragma unroll
  for (int e = 0; e < EEXP; ++e) {
    int n = sCnt[e], b = sBase[e];
    for (int i = tid; i < n; i += 256) {
      slots[e * CAP + b + i] = sSlot[e][i];
      wlist[e * CAP + b + i] = sWt[e][i];
    }
  }
}

// ---------------- finalize aux losses ----------------
__global__ void finalize_kernel(const int* __restrict__ cnt, const float* __restrict__ imp,
                                const float* __restrict__ ent, float* __restrict__ outl) {
  if (threadIdx.x == 0 && blockIdx.x == 0) {
    float lb = 0.f;
    for (int e = 0; e < EEXP; ++e)
      lb += (imp[e << 4] / (float)TTOK) * ((float)cnt[e << 4] / (float)(TTOK * 2));
    lb *= (float)EEXP;
    float el = ent[0] / (float)TTOK;
    outl[0] = lb;
    outl[1] = el;
    outl[2] = 0.01f * lb;   // + 0.0f * ent
  }
}

// ---------------- fused GEMM1+GEMM2+SiLU -> Hid (bf16) ----------------
// Round-12: r8's 256M x 128N / 8-wave / 64 KiB shape (correctness proven in
// r8; perf was masked by gemm3's spill). bf16 weights via cvt (r11 showed
// fp32-direct dual-B staging costs more inside this kernel than the cvt).
// 2 blocks/CU x 8 waves = 16 waves/CU; grid 512 active = single round.
__global__ __launch_bounds__(512, 2) void gemm12_kernel(
    const unsigned short* __restrict__ xb,   // [T][D]
    const unsigned short* __restrict__ W1b,  // [E][H][D]
    const unsigned short* __restrict__ W2b,  // [E][H][D]
    unsigned short* __restrict__ Hid,        // [2T][H]
    const int* __restrict__ cnt,             // padded: cnt[e*16]
    const int* __restrict__ slots)           // [E][CAP]
{
  const int e = blockIdx.z;
  const int ne = cnt[e << 4];
  const int m0 = blockIdx.y * 256;
  if (m0 >= ne) return;
  const int n0 = blockIdx.x * 128;

  __shared__ unsigned short sA[256 * 64];    // 32 KiB
  __shared__ unsigned short sB1[128 * 64];   // 16 KiB
  __shared__ unsigned short sB2[128 * 64];   // 16 KiB

  const int tid = threadIdx.x;
  const int lane = tid & 63;
  const int wv = tid >> 6;                 // 0..7
  const int wm = wv >> 1, wn = wv & 1;     // 4M x 2N waves
  const int* eslots = slots + e * CAP;

  // staging: row = (tid>>3) + i*64 (row&7 == (tid>>3)&7); source slot
  // pre-swizzled, gl16 LDS dest linear (lane-contiguous).
  const int cole = ((tid & 7) ^ ((tid >> 3) & 7)) * 8;
  const unsigned short* gA[4];
  const unsigned short* gB1[2];
  const unsigned short* gB2[2];
  char* lA[4]; char* lB1[2]; char* lB2[2];
  const size_t wbase = (size_t)e * HDIM * DDIM;
#pragma unroll
  for (int i = 0; i < 4; ++i) {
    int p = m0 + (tid >> 3) + i * 64;
    int sl = eslots[(p < ne) ? p : 0];
    gA[i] = xb + (size_t)(sl >> 1) * DDIM + cole;
    lA[i] = (char*)sA + i * 8192 + (tid & ~63) * 16;
  }
#pragma unroll
  for (int i = 0; i < 2; ++i) {
    int r = n0 + (tid >> 3) + i * 64;
    gB1[i] = W1b + wbase + (size_t)r * DDIM + cole;
    gB2[i] = W2b + wbase + (size_t)r * DDIM + cole;
    lB1[i] = (char*)sB1 + i * 8192 + (tid & ~63) * 16;
    lB2[i] = (char*)sB2 + i * 8192 + (tid & ~63) * 16;
  }

  f32x4 acc1[4][4], acc2[4][4];
#pragma unroll
  for (int m = 0; m < 4; ++m)
#pragma unroll
    for (int n = 0; n < 4; ++n) {
      acc1[m][n] = f32x4{0.f, 0.f, 0.f, 0.f};
      acc2[m][n] = f32x4{0.f, 0.f, 0.f, 0.f};
    }

  const int fr = lane & 15;
  const int g = lane >> 4;
  const int frx = fr & 7;            // read-side XOR key (row&7 == fr&7)

  for (int kt = 0; kt < DDIM / 64; ++kt) {
#pragma unroll
    for (int i = 0; i < 4; ++i) { gl16(gA[i], lA[i]); gA[i] += 64; }
#pragma unroll
    for (int i = 0; i < 2; ++i) {
      gl16(gB1[i], lB1[i]); gB1[i] += 64;
      gl16(gB2[i], lB2[i]); gB2[i] += 64;
    }
    __syncthreads();
#pragma unroll
    for (int kk = 0; kk < 2; ++kk) {
      bfrag a[4], b1[4], b2[4];
      const int so = ((kk * 4 + g) ^ frx) * 8;   // swizzled slot offset (elems)
#pragma unroll
      for (int m = 0; m < 4; ++m)
        a[m] = *(const bfrag*)&sA[(wm * 64 + m * 16 + fr) * 64 + so];
#pragma unroll
      for (int n = 0; n < 4; ++n) {
        b1[n] = *(const bfrag*)&sB1[(wn * 64 + n * 16 + fr) * 64 + so];
        b2[n] = *(const bfrag*)&sB2[(wn * 64 + n * 16 + fr) * 64 + so];
      }
#pragma unroll
      for (int m = 0; m < 4; ++m)
#pragma unroll
        for (int n = 0; n < 4; ++n) {
          acc1[m][n] = __builtin_amdgcn_mfma_f32_16x16x32_bf16(a[m], b1[n], acc1[m][n], 0, 0, 0);
          acc2[m][n] = __builtin_amdgcn_mfma_f32_16x16x32_bf16(a[m], b2[n], acc2[m][n], 0, 0, 0);
        }
    }
    __syncthreads();
  }

  const int rb = g * 4;
#pragma unroll
  for (int m = 0; m < 4; ++m) {
#pragma unroll
    for (int j = 0; j < 4; ++j) {
      int p = m0 + wm * 64 + m * 16 + rb + j;
      if (p >= ne) continue;
      size_t srow = (size_t)eslots[p] * HDIM;
#pragma unroll
      for (int n = 0; n < 4; ++n) {
        int col = n0 + wn * 64 + n * 16 + fr;
        float c1 = acc1[m][n][j], c2 = acc2[m][n][j];
        float h = c1 / (1.f + __expf(-c1)) * c2;
        Hid[srow + col] = f2bf(h);
      }
    }
  }
}

// ---------------- GEMM3: y += w * (Hid @ W3^T) ----------------
// r11 version (verified): fp32 W3 read directly, in-register cvt, swizzled
// ds_write; 128x128, BK=64, K-split x2, 32 KiB LDS, allocator-free VGPR.
__global__ __launch_bounds__(256, 2) void gemm3_kernel(
    const unsigned short* __restrict__ Hid,  // [2T][H] bf16
    const float* __restrict__ W3f,           // [E][D][H] fp32
    float* __restrict__ y,                   // [T][D]
    const int* __restrict__ cnt,             // padded: cnt[e*16]
    const int* __restrict__ slots,
    const float* __restrict__ wlist)
{
  const int e  = blockIdx.z >> 1;
  const int ks = blockIdx.z & 1;           // K half: cols ks*1024 .. +1023
  const int ne = cnt[e << 4];
  const int m0 = blockIdx.y * 128;
  if (m0 >= ne) return;
  const int n0 = blockIdx.x * 128;

  __shared__ unsigned short sA[128 * 64];   // 16 KiB
  __shared__ unsigned short sB[128 * 64];   // 16 KiB

  const int tid = threadIdx.x;
  const int lane = tid & 63;
  const int wv = tid >> 6;
  const int wr = wv >> 1, wc = wv & 1;     // 2M x 2N waves
  const int* eslots = slots + e * CAP;

  const int cole = ((tid & 7) ^ ((tid >> 3) & 7)) * 8;  // pre-swizzled src slot
  const unsigned short* gA[4];
  char* lA[4];
#pragma unroll
  for (int i = 0; i < 4; ++i) {
    int p = m0 + (tid >> 3) + i * 32;
    int sl = eslots[(p < ne) ? p : 0];
    gA[i] = Hid + (size_t)sl * HDIM + ks * 1024 + cole;
    lA[i] = (char*)sA + (size_t)(i * 256 + (tid & ~63)) * 16;
  }

  const int swz16 = ((tid & 7) ^ ((tid >> 3) & 7)) * 16;
  const float* gB[4];
  char* lBw[4];
  const size_t wbase = (size_t)e * DDIM * HDIM;
#pragma unroll
  for (int i = 0; i < 4; ++i) {
    int r = i * 32 + (tid >> 3);
    gB[i] = W3f + wbase + (size_t)(n0 + r) * HDIM + ks * 1024 + (tid & 7) * 8;
    lBw[i] = (char*)sB + r * 128 + swz16;
  }

  f32x4 acc[4][4];
#pragma unroll
  for (int m = 0; m < 4; ++m)
#pragma unroll
    for (int n = 0; n < 4; ++n) acc[m][n] = f32x4{0.f, 0.f, 0.f, 0.f};

  const int fr = lane & 15;
  const int g = lane >> 4;
  const int frx = fr & 7;

  for (int kt = 0; kt < 16; ++kt) {        // K=1024 per split, BK=64
#pragma unroll
    for (int i = 0; i < 4; ++i) { gl16(gA[i], lA[i]); gA[i] += 64; }
#pragma unroll
    for (int i = 0; i < 4; ++i) {
      float4 a0 = ((const float4*)gB[i])[0];
      float4 a1 = ((const float4*)gB[i])[1];
      *(uint4*)lBw[i] = pack8(a0, a1);
      gB[i] += 64;
    }
    __syncthreads();
#pragma unroll
    for (int kk = 0; kk < 2; ++kk) {
      bfrag a[4], b[4];
      const int so = ((kk * 4 + g) ^ frx) * 8;
#pragma unroll
      for (int m = 0; m < 4; ++m)
        a[m] = *(const bfrag*)&sA[(wr * 64 + m * 16 + fr) * 64 + so];
#pragma unroll
      for (int n = 0; n < 4; ++n)
        b[n] = *(const bfrag*)&sB[(wc * 64 + n * 16 + fr) * 64 + so];
#pragma unroll
      for (int m = 0; m < 4; ++m)
#pragma unroll
        for (int n = 0; n < 4; ++n)
          acc[m][n] = __builtin_amdgcn_mfma_f32_16x16x32_bf16(a[m], b[n], acc[m][n], 0, 0, 0);
    }
    __syncthreads();
  }

  const int rb = g * 4;
#pragma unroll
  for (int m = 0; m < 4; ++m) {
#pragma unroll
    for (int j = 0; j < 4; ++j) {
      int p = m0 + wr * 64 + m * 16 + rb + j;
      if (p >= ne) continue;
      int sl = eslots[p];
      float w = wlist[e * CAP + p];
      float* yrow = y + (size_t)(sl >> 1) * DDIM;
#pragma unroll
      for (int n = 0; n < 4; ++n) {
        int col = n0 + wc * 64 + n * 16 + fr;
        unsafeAtomicAdd(&yrow[col], acc[m][n][j] * w);
      }
    }
  }
}

// ---------------- launcher ----------------
extern "C" void kernel_launch(void* const* d_in, const int* in_sizes, int n_in,
                              void* d_out, int out_size, void* d_ws, size_t ws_size,
                              hipStream_t stream) {
  const float* x  = (const float*)d_in[0];
  const float* Wg = (const float*)d_in[1];
  const float* W1 = (const float*)d_in[2];
  const float* W2 = (const float*)d_in[3];
  const float* W3 = (const float*)d_in[4];
  float* y    = (float*)d_out;
  float* outl = y + (size_t)TTOK * DDIM;

  char* ws = (char*)d_ws;
  size_t off = 0;
  auto alloc = [&](size_t bytes) {
    char* p = ws + off;
    off += (bytes + 255) & ~(size_t)255;
    return p;
  };
  unsigned short* xb  = (unsigned short*)alloc((size_t)TTOK * DDIM * 2);
  unsigned short* W1b = (unsigned short*)alloc((size_t)EEXP * HDIM * DDIM * 2);
  unsigned short* W2b = (unsigned short*)alloc((size_t)EEXP * HDIM * DDIM * 2);
  unsigned short* Hid = (unsigned short*)alloc((size_t)TTOK * 2 * HDIM * 2);
  int*   slots = (int*)alloc(EEXP * CAP * 4);
  float* wlist = (float*)alloc(EEXP * CAP * 4);
  char* hdr = alloc(1536);                 // padded: cnt 512B | imp 512B | ent
  int*   cnt = (int*)hdr;                  // cnt[e*16]
  float* imp = (float*)(hdr + 512);        // imp[e*16]
  float* ent = (float*)(hdr + 1024);
  if (ws_size < off) return;  // workspace too small — bail cleanly

  hipMemsetAsync(d_out, 0, (size_t)TTOK * DDIM * sizeof(float), stream);
  hipMemsetAsync(hdr, 0, 1536, stream);

  cvt_kernel<<<2048, 256, 0, stream>>>((const float4*)x,  (ushort4*)xb,  TTOK * DDIM / 4);
  cvt_kernel<<<4096, 256, 0, stream>>>((const float4*)W1, (ushort4*)W1b, EEXP * HDIM * DDIM / 4);
  cvt_kernel<<<4096, 256, 0, stream>>>((const float4*)W2, (ushort4*)W2b, EEXP * HDIM * DDIM / 4);

  gating_kernel<<<TTOK / GBLK, 256, 0, stream>>>(x, Wg, cnt, imp, ent, slots, wlist);
  finalize_kernel<<<1, 64, 0, stream>>>(cnt, imp, ent, outl);

  gemm12_kernel<<<dim3(HDIM / 128, CAP / 256, EEXP), 512, 0, stream>>>(
      xb, W1b, W2b, Hid, cnt, slots);

  gemm3_kernel<<<dim3(DDIM / 128, CAP / 128, EEXP * 2), 256, 0, stream>>>(
      Hid, W3, y, cnt, slots, wlist);
}

// Round 13
// 275.482 us; speedup vs baseline: 1.1835x; 1.1835x over previous
//
#include <hip/hip_runtime.h>
#include <stdint.h>

#define DDIM 1024
#define HDIM 2048
#define EEXP 8
#define TTOK 4096   // B*S
#define CAP  4096   // max tokens per expert
#define GBLK 32     // tokens per gating block

using f32x4 = __attribute__((ext_vector_type(4))) float;
using bfrag = __attribute__((ext_vector_type(8))) short;   // 8 bf16 (4 VGPRs)

__device__ __forceinline__ unsigned short f2bf(float f) {
  unsigned u = __builtin_bit_cast(unsigned, f);
  return (unsigned short)((u + 0x7fffu + ((u >> 16) & 1u)) >> 16);  // RNE
}

__device__ __forceinline__ void gl16(const void* g, void* l) {
  __builtin_amdgcn_global_load_lds(
      (const __attribute__((address_space(1))) unsigned int*)g,
      (__attribute__((address_space(3))) unsigned int*)l, 16, 0, 0);
}

// ---------------- fp32 -> bf16 conversion (W1, W2, W3) ----------------
__global__ void cvt_kernel(const float4* __restrict__ src, ushort4* __restrict__ dst, int n4) {
  int i = blockIdx.x * blockDim.x + threadIdx.x;
  int st = gridDim.x * blockDim.x;
  for (; i < n4; i += st) {
    float4 v = src[i];
    ushort4 o;
    o.x = f2bf(v.x); o.y = f2bf(v.y); o.z = f2bf(v.z); o.w = f2bf(v.w);
    dst[i] = o;
  }
}

// ---------------- gating: block-local aggregation + fused x->bf16 ----------------
// r10-verified structure. New in r13: gating already streams every element of
// x through registers, so it emits xb (bf16 x) itself -> the standalone cvt-x
// dispatch is deleted. Costs ~5us of writes in a kernel at 1% HBM utilization.
__global__ __launch_bounds__(256) void gating_kernel(
    const float* __restrict__ x, const float* __restrict__ Wg,
    unsigned short* __restrict__ xb,   // [T][D] bf16 out
    int* __restrict__ cnt,      // padded: cnt[e*16]
    float* __restrict__ imp,    // padded: imp[e*16]
    float* __restrict__ entacc,
    int* __restrict__ slots, float* __restrict__ wlist)
{
  __shared__ float sWg[EEXP * DDIM];     // 32 KB
  __shared__ float sImp[EEXP];
  __shared__ float sEnt;
  __shared__ int   sCnt[EEXP];
  __shared__ int   sBase[EEXP];
  __shared__ int   sSlot[EEXP][GBLK];
  __shared__ float sWt[EEXP][GBLK];

  const int tid = threadIdx.x;
  for (int i = tid; i < EEXP * DDIM / 4; i += 256)
    ((float4*)sWg)[i] = ((const float4*)Wg)[i];
  if (tid < EEXP) { sImp[tid] = 0.f; sCnt[tid] = 0; }
  if (tid == EEXP) sEnt = 0.f;
  __syncthreads();

  const int wv = tid >> 6, lane = tid & 63;
  float impAcc[EEXP];
#pragma unroll
  for (int e = 0; e < EEXP; ++e) impAcc[e] = 0.f;
  float entAcc = 0.f;

  for (int it = 0; it < GBLK / 4; ++it) {          // 8 tokens per wave
    const int t = blockIdx.x * GBLK + wv * (GBLK / 4) + it;
    const float4* xt4 = (const float4*)(x + (size_t)t * DDIM);
    ushort4* xbt4 = (ushort4*)(xb + (size_t)t * DDIM);
    float s[EEXP];
#pragma unroll
    for (int e = 0; e < EEXP; ++e) s[e] = 0.f;
#pragma unroll
    for (int i = 0; i < DDIM / 256; ++i) {
      float4 xv = xt4[i * 64 + lane];
      ushort4 xo;
      xo.x = f2bf(xv.x); xo.y = f2bf(xv.y); xo.z = f2bf(xv.z); xo.w = f2bf(xv.w);
      xbt4[i * 64 + lane] = xo;
#pragma unroll
      for (int e = 0; e < EEXP; ++e) {
        float4 w4 = ((const float4*)sWg)[e * (DDIM / 4) + i * 64 + lane];
        s[e] += xv.x * w4.x + xv.y * w4.y + xv.z * w4.z + xv.w * w4.w;
      }
    }
#pragma unroll
    for (int off = 32; off > 0; off >>= 1) {
#pragma unroll
      for (int e = 0; e < EEXP; ++e) s[e] += __shfl_xor(s[e], off);
    }
    if (lane == 0) {
      float m = s[0];
#pragma unroll
      for (int e = 1; e < EEXP; ++e) m = fmaxf(m, s[e]);
      float ex[EEXP], sum = 0.f;
#pragma unroll
      for (int e = 0; e < EEXP; ++e) { ex[e] = __expf(s[e] - m); sum += ex[e]; }
      float inv = 1.f / sum;
#pragma unroll
      for (int e = 0; e < EEXP; ++e) {
        float p = ex[e] * inv;
        impAcc[e] += p;
        entAcc += p * __logf(fmaxf(p, 1e-9f));
      }
      // top-2, strict > keeps lowest index on ties (matches jax.lax.top_k)
      int e0 = 0;
#pragma unroll
      for (int e = 1; e < EEXP; ++e) if (s[e] > s[e0]) e0 = e;
      int e1 = (e0 == 0) ? 1 : 0;
#pragma unroll
      for (int e = 0; e < EEXP; ++e) if (e != e0 && s[e] > s[e1]) e1 = e;
      float tt = __expf(s[e1] - s[e0]);
      float p0 = 1.f / (1.f + tt);
      float p1 = tt / (1.f + tt);
      int pos0 = atomicAdd(&sCnt[e0], 1);
      sSlot[e0][pos0] = t * 2;     sWt[e0][pos0] = p0;
      int pos1 = atomicAdd(&sCnt[e1], 1);
      sSlot[e1][pos1] = t * 2 + 1; sWt[e1][pos1] = p1;
    }
  }
  if (lane == 0) {
#pragma unroll
    for (int e = 0; e < EEXP; ++e) atomicAdd(&sImp[e], impAcc[e]);
    atomicAdd(&sEnt, entAcc);
  }
  __syncthreads();
  if (tid < EEXP) {
    sBase[tid] = atomicAdd(&cnt[tid << 4], sCnt[tid]);   // padded line per expert
    atomicAdd(&imp[tid << 4], sImp[tid]);
  }
  if (tid == EEXP) atomicAdd(entacc, sEnt);
  __syncthreads();
#pragma unroll
  for (int e = 0; e < EEXP; ++e) {
    int n = sCnt[e], b = sBase[e];
    for (int i = tid; i < n; i += 256) {
      slots[e * CAP + b + i] = sSlot[e][i];
      wlist[e * CAP + b + i] = sWt[e][i];
    }
  }
}

// ---------------- finalize aux losses ----------------
__global__ void finalize_kernel(const int* __restrict__ cnt, const float* __restrict__ imp,
                                const float* __restrict__ ent, float* __restrict__ outl) {
  if (threadIdx.x == 0 && blockIdx.x == 0) {
    float lb = 0.f;
    for (int e = 0; e < EEXP; ++e)
      lb += (imp[e << 4] / (float)TTOK) * ((float)cnt[e << 4] / (float)(TTOK * 2));
    lb *= (float)EEXP;
    float el = ent[0] / (float)TTOK;
    outl[0] = lb;
    outl[1] = el;
    outl[2] = 0.01f * lb;   // + 0.0f * ent
  }
}

// ---------------- fused GEMM1+GEMM2+SiLU -> Hid (bf16) ----------------
// r10-exact (measured ~90us): 128x128, BK=64, 4 waves, both-sides XOR swizzle.
__global__ __launch_bounds__(256, 2) void gemm12_kernel(
    const unsigned short* __restrict__ xb,   // [T][D]
    const unsigned short* __restrict__ W1b,  // [E][H][D]
    const unsigned short* __restrict__ W2b,  // [E][H][D]
    unsigned short* __restrict__ Hid,        // [2T][H]
    const int* __restrict__ cnt,             // padded: cnt[e*16]
    const int* __restrict__ slots)           // [E][CAP]
{
  const int e = blockIdx.z;
  const int ne = cnt[e << 4];
  const int m0 = blockIdx.y * 128;
  if (m0 >= ne) return;
  const int n0 = blockIdx.x * 128;

  __shared__ unsigned short sA[128 * 64];
  __shared__ unsigned short sB1[128 * 64];
  __shared__ unsigned short sB2[128 * 64];

  const int tid = threadIdx.x;
  const int lane = tid & 63;
  const int wv = tid >> 6;
  const int wr = wv >> 1, wc = wv & 1;
  const int* eslots = slots + e * CAP;

  // stage source column: slot (tid&7) XOR row&7 ((tid>>3)&7), 16B granules
  const int cole = ((tid & 7) ^ ((tid >> 3) & 7)) * 8;
  const unsigned short* gA[4];
  const unsigned short* gB1[4];
  const unsigned short* gB2[4];
  char* lA[4]; char* lB1[4]; char* lB2[4];
  const size_t wbase = (size_t)e * HDIM * DDIM;
#pragma unroll
  for (int i = 0; i < 4; ++i) {
    int p = m0 + (tid >> 3) + i * 32;
    int sl = eslots[(p < ne) ? p : 0];
    gA[i]  = xb + (size_t)(sl >> 1) * DDIM + cole;
    int r = i * 32 + (tid >> 3);
    gB1[i] = W1b + wbase + (size_t)(n0 + r) * DDIM + cole;
    gB2[i] = W2b + wbase + (size_t)(n0 + r) * DDIM + cole;
    lA[i]  = (char*)sA  + (size_t)(i * 256 + (tid & ~63)) * 16;
    lB1[i] = (char*)sB1 + (size_t)(i * 256 + (tid & ~63)) * 16;
    lB2[i] = (char*)sB2 + (size_t)(i * 256 + (tid & ~63)) * 16;
  }

  f32x4 acc1[4][4], acc2[4][4];
#pragma unroll
  for (int m = 0; m < 4; ++m)
#pragma unroll
    for (int n = 0; n < 4; ++n) {
      acc1[m][n] = f32x4{0.f, 0.f, 0.f, 0.f};
      acc2[m][n] = f32x4{0.f, 0.f, 0.f, 0.f};
    }

  const int fr = lane & 15;
  const int g = lane >> 4;
  const int frx = fr & 7;            // read-side XOR key (row&7 == fr&7)

  for (int kt = 0; kt < DDIM / 64; ++kt) {
#pragma unroll
    for (int i = 0; i < 4; ++i) {
      gl16(gA[i],  lA[i]);  gA[i]  += 64;
      gl16(gB1[i], lB1[i]); gB1[i] += 64;
      gl16(gB2[i], lB2[i]); gB2[i] += 64;
    }
    __syncthreads();
#pragma unroll
    for (int kk = 0; kk < 2; ++kk) {
      bfrag a[4], b1[4], b2[4];
      const int so = ((kk * 4 + g) ^ frx) * 8;   // swizzled slot offset (elems)
#pragma unroll
      for (int m = 0; m < 4; ++m)
        a[m] = *(const bfrag*)&sA[(wr * 64 + m * 16 + fr) * 64 + so];
#pragma unroll
      for (int n = 0; n < 4; ++n) {
        b1[n] = *(const bfrag*)&sB1[(wc * 64 + n * 16 + fr) * 64 + so];
        b2[n] = *(const bfrag*)&sB2[(wc * 64 + n * 16 + fr) * 64 + so];
      }
#pragma unroll
      for (int m = 0; m < 4; ++m)
#pragma unroll
        for (int n = 0; n < 4; ++n) {
          acc1[m][n] = __builtin_amdgcn_mfma_f32_16x16x32_bf16(a[m], b1[n], acc1[m][n], 0, 0, 0);
          acc2[m][n] = __builtin_amdgcn_mfma_f32_16x16x32_bf16(a[m], b2[n], acc2[m][n], 0, 0, 0);
        }
    }
    __syncthreads();
  }

  const int rb = g * 4;
#pragma unroll
  for (int m = 0; m < 4; ++m) {
#pragma unroll
    for (int j = 0; j < 4; ++j) {
      int p = m0 + wr * 64 + m * 16 + rb + j;
      if (p >= ne) continue;
      size_t srow = (size_t)eslots[p] * HDIM;
#pragma unroll
      for (int n = 0; n < 4; ++n) {
        int col = n0 + wc * 64 + n * 16 + fr;
        float c1 = acc1[m][n][j], c2 = acc2[m][n][j];
        float h = c1 / (1.f + __expf(-c1)) * c2;
        Hid[srow + col] = f2bf(h);
      }
    }
  }
}

// ---------------- GEMM3: y += w * (Hid @ W3^T) ----------------
// r10-exact (measured ~95us): bf16 W3 via cvt, 128x128, BK=64, K-split x2,
// 32 KiB LDS, allocator-free VGPR. (fp32-direct W3 measured 148us in r12 —
// reg-staged pack chain costs more than the 30us cvt it saves.)
__global__ __launch_bounds__(256, 2) void gemm3_kernel(
    const unsigned short* __restrict__ Hid,  // [2T][H]
    const unsigned short* __restrict__ W3b,  // [E][D][H]
    float* __restrict__ y,                   // [T][D]
    const int* __restrict__ cnt,             // padded: cnt[e*16]
    const int* __restrict__ slots,
    const float* __restrict__ wlist)
{
  const int e  = blockIdx.z >> 1;
  const int ks = blockIdx.z & 1;           // K half: cols ks*1024 .. +1023
  const int ne = cnt[e << 4];
  const int m0 = blockIdx.y * 128;
  if (m0 >= ne) return;
  const int n0 = blockIdx.x * 128;

  __shared__ unsigned short sA[128 * 64];   // 16 KiB
  __shared__ unsigned short sB[128 * 64];   // 16 KiB

  const int tid = threadIdx.x;
  const int lane = tid & 63;
  const int wv = tid >> 6;
  const int wr = wv >> 1, wc = wv & 1;     // 2M x 2N waves
  const int* eslots = slots + e * CAP;

  const int cole = ((tid & 7) ^ ((tid >> 3) & 7)) * 8;  // pre-swizzled src slot
  const unsigned short* gA[4];
  const unsigned short* gB[4];
  char* lA[4]; char* lB[4];
  const size_t wbase = (size_t)e * DDIM * HDIM;
#pragma unroll
  for (int i = 0; i < 4; ++i) {
    int p = m0 + (tid >> 3) + i * 32;
    int sl = eslots[(p < ne) ? p : 0];
    gA[i] = Hid + (size_t)sl * HDIM + ks * 1024 + cole;
    int r = n0 + (tid >> 3) + i * 32;
    gB[i] = W3b + wbase + (size_t)r * HDIM + ks * 1024 + cole;
    lA[i] = (char*)sA + (size_t)(i * 256 + (tid & ~63)) * 16;
    lB[i] = (char*)sB + (size_t)(i * 256 + (tid & ~63)) * 16;
  }

  f32x4 acc[4][4];
#pragma unroll
  for (int m = 0; m < 4; ++m)
#pragma unroll
    for (int n = 0; n < 4; ++n) acc[m][n] = f32x4{0.f, 0.f, 0.f, 0.f};

  const int fr = lane & 15;
  const int g = lane >> 4;
  const int frx = fr & 7;

  for (int kt = 0; kt < 16; ++kt) {        // K=1024 per split, BK=64
#pragma unroll
    for (int i = 0; i < 4; ++i) {
      gl16(gA[i], lA[i]); gA[i] += 64;
      gl16(gB[i], lB[i]); gB[i] += 64;
    }
    __syncthreads();
#pragma unroll
    for (int kk = 0; kk < 2; ++kk) {
      bfrag a[4], b[4];
      const int so = ((kk * 4 + g) ^ frx) * 8;
#pragma unroll
      for (int m = 0; m < 4; ++m)
        a[m] = *(const bfrag*)&sA[(wr * 64 + m * 16 + fr) * 64 + so];
#pragma unroll
      for (int n = 0; n < 4; ++n)
        b[n] = *(const bfrag*)&sB[(wc * 64 + n * 16 + fr) * 64 + so];
#pragma unroll
      for (int m = 0; m < 4; ++m)
#pragma unroll
        for (int n = 0; n < 4; ++n)
          acc[m][n] = __builtin_amdgcn_mfma_f32_16x16x32_bf16(a[m], b[n], acc[m][n], 0, 0, 0);
    }
    __syncthreads();
  }

  const int rb = g * 4;
#pragma unroll
  for (int m = 0; m < 4; ++m) {
#pragma unroll
    for (int j = 0; j < 4; ++j) {
      int p = m0 + wr * 64 + m * 16 + rb + j;
      if (p >= ne) continue;
      int sl = eslots[p];
      float w = wlist[e * CAP + p];
      float* yrow = y + (size_t)(sl >> 1) * DDIM;
#pragma unroll
      for (int n = 0; n < 4; ++n) {
        int col = n0 + wc * 64 + n * 16 + fr;
        unsafeAtomicAdd(&yrow[col], acc[m][n][j] * w);
      }
    }
  }
}

// ---------------- launcher ----------------
extern "C" void kernel_launch(void* const* d_in, const int* in_sizes, int n_in,
                              void* d_out, int out_size, void* d_ws, size_t ws_size,
                              hipStream_t stream) {
  const float* x  = (const float*)d_in[0];
  const float* Wg = (const float*)d_in[1];
  const float* W1 = (const float*)d_in[2];
  const float* W2 = (const float*)d_in[3];
  const float* W3 = (const float*)d_in[4];
  float* y    = (float*)d_out;
  float* outl = y + (size_t)TTOK * DDIM;

  char* ws = (char*)d_ws;
  size_t off = 0;
  auto alloc = [&](size_t bytes) {
    char* p = ws + off;
    off += (bytes + 255) & ~(size_t)255;
    return p;
  };
  unsigned short* xb  = (unsigned short*)alloc((size_t)TTOK * DDIM * 2);
  unsigned short* W1b = (unsigned short*)alloc((size_t)EEXP * HDIM * DDIM * 2);  // reused for W3b later
  unsigned short* W2b = (unsigned short*)alloc((size_t)EEXP * HDIM * DDIM * 2);
  unsigned short* Hid = (unsigned short*)alloc((size_t)TTOK * 2 * HDIM * 2);
  int*   slots = (int*)alloc(EEXP * CAP * 4);
  float* wlist = (float*)alloc(EEXP * CAP * 4);
  char* hdr = alloc(1536);                 // padded: cnt 512B | imp 512B | ent
  int*   cnt = (int*)hdr;                  // cnt[e*16]
  float* imp = (float*)(hdr + 512);        // imp[e*16]
  float* ent = (float*)(hdr + 1024);
  if (ws_size < off) return;  // workspace too small — bail cleanly

  hipMemsetAsync(d_out, 0, (size_t)TTOK * DDIM * sizeof(float), stream);
  hipMemsetAsync(hdr, 0, 1536, stream);

  gating_kernel<<<TTOK / GBLK, 256, 0, stream>>>(x, Wg, xb, cnt, imp, ent, slots, wlist);
  finalize_kernel<<<1, 64, 0, stream>>>(cnt, imp, ent, outl);

  cvt_kernel<<<4096, 256, 0, stream>>>((const float4*)W1, (ushort4*)W1b, EEXP * HDIM * DDIM / 4);
  cvt_kernel<<<4096, 256, 0, stream>>>((const float4*)W2, (ushort4*)W2b, EEXP * HDIM * DDIM / 4);

  gemm12_kernel<<<dim3(HDIM / 128, CAP / 128, EEXP), 256, 0, stream>>>(
      xb, W1b, W2b, Hid, cnt, slots);

  // W1b no longer needed -> reuse for bf16 W3
  cvt_kernel<<<4096, 256, 0, stream>>>((const float4*)W3, (ushort4*)W1b, EEXP * DDIM * HDIM / 4);

  gemm3_kernel<<<dim3(DDIM / 128, CAP / 128, EEXP * 2), 256, 0, stream>>>(
      Hid, W1b, y, cnt, slots, wlist);
}

// Round 14
// 251.250 us; speedup vs baseline: 1.2977x; 1.0964x over previous
//
#include <hip/hip_runtime.h>
#include <stdint.h>

#define DDIM 1024
#define HDIM 2048
#define EEXP 8
#define TTOK 4096   // B*S
#define CAP  4096   // max tokens per expert
#define GBLK 32     // tokens per gating block
#define GATB (TTOK / GBLK)   // 128 gating blocks
#define CVTB 1024            // cvt blocks in prep_kernel

using f32x4 = __attribute__((ext_vector_type(4))) float;
using bfrag = __attribute__((ext_vector_type(8))) short;   // 8 bf16 (4 VGPRs)

__device__ __forceinline__ unsigned short f2bf(float f) {
  unsigned u = __builtin_bit_cast(unsigned, f);
  return (unsigned short)((u + 0x7fffu + ((u >> 16) & 1u)) >> 16);  // RNE
}

__device__ __forceinline__ void gl16(const void* g, void* l) {
  __builtin_amdgcn_global_load_lds(
      (const __attribute__((address_space(1))) unsigned int*)g,
      (__attribute__((address_space(3))) unsigned int*)l, 16, 0, 0);
}

__device__ __forceinline__ void cvt_stride(const float4* __restrict__ src,
                                           ushort4* __restrict__ dst,
                                           int i, int stride, int n4) {
  for (; i < n4; i += stride) {
    float4 v = src[i];
    ushort4 o;
    o.x = f2bf(v.x); o.y = f2bf(v.y); o.z = f2bf(v.z); o.w = f2bf(v.w);
    dst[i] = o;
  }
}

// ---------------- prep: gating (blocks 0..127) || W1/W2 cvt (blocks 128..) ----------------
// Gating body = r13-verified (block-local aggregation, fused x->bf16, padded
// global atomics). cvt blocks are pure BW work using the CUs/BW gating leaves
// idle; disjoint data, one dispatch instead of three.
__global__ __launch_bounds__(256) void prep_kernel(
    const float* __restrict__ x, const float* __restrict__ Wg,
    unsigned short* __restrict__ xb,
    const float* __restrict__ W1, const float* __restrict__ W2,
    unsigned short* __restrict__ W1b, unsigned short* __restrict__ W2b,
    int* __restrict__ cnt, float* __restrict__ imp, float* __restrict__ entacc,
    int* __restrict__ slots, float* __restrict__ wlist)
{
  __shared__ float sWg[EEXP * DDIM];     // 32 KB
  __shared__ float sImp[EEXP];
  __shared__ float sEnt;
  __shared__ int   sCnt[EEXP];
  __shared__ int   sBase[EEXP];
  __shared__ int   sSlot[EEXP][GBLK];
  __shared__ float sWt[EEXP][GBLK];

  const int tid = threadIdx.x;

  if (blockIdx.x >= GATB) {
    // -------- weight conversion plane --------
    const int b = blockIdx.x - GATB;             // 0..CVTB-1
    const int n4 = EEXP * HDIM * DDIM / 4;
    const int i0 = b * 256 + tid;
    cvt_stride((const float4*)W1, (ushort4*)W1b, i0, CVTB * 256, n4);
    cvt_stride((const float4*)W2, (ushort4*)W2b, i0, CVTB * 256, n4);
    return;
  }

  // -------- gating plane (r13 body) --------
  for (int i = tid; i < EEXP * DDIM / 4; i += 256)
    ((float4*)sWg)[i] = ((const float4*)Wg)[i];
  if (tid < EEXP) { sImp[tid] = 0.f; sCnt[tid] = 0; }
  if (tid == EEXP) sEnt = 0.f;
  __syncthreads();

  const int wv = tid >> 6, lane = tid & 63;
  float impAcc[EEXP];
#pragma unroll
  for (int e = 0; e < EEXP; ++e) impAcc[e] = 0.f;
  float entAcc = 0.f;

  for (int it = 0; it < GBLK / 4; ++it) {          // 8 tokens per wave
    const int t = blockIdx.x * GBLK + wv * (GBLK / 4) + it;
    const float4* xt4 = (const float4*)(x + (size_t)t * DDIM);
    ushort4* xbt4 = (ushort4*)(xb + (size_t)t * DDIM);
    float s[EEXP];
#pragma unroll
    for (int e = 0; e < EEXP; ++e) s[e] = 0.f;
#pragma unroll
    for (int i = 0; i < DDIM / 256; ++i) {
      float4 xv = xt4[i * 64 + lane];
      ushort4 xo;
      xo.x = f2bf(xv.x); xo.y = f2bf(xv.y); xo.z = f2bf(xv.z); xo.w = f2bf(xv.w);
      xbt4[i * 64 + lane] = xo;
#pragma unroll
      for (int e = 0; e < EEXP; ++e) {
        float4 w4 = ((const float4*)sWg)[e * (DDIM / 4) + i * 64 + lane];
        s[e] += xv.x * w4.x + xv.y * w4.y + xv.z * w4.z + xv.w * w4.w;
      }
    }
#pragma unroll
    for (int off = 32; off > 0; off >>= 1) {
#pragma unroll
      for (int e = 0; e < EEXP; ++e) s[e] += __shfl_xor(s[e], off);
    }
    if (lane == 0) {
      float m = s[0];
#pragma unroll
      for (int e = 1; e < EEXP; ++e) m = fmaxf(m, s[e]);
      float ex[EEXP], sum = 0.f;
#pragma unroll
      for (int e = 0; e < EEXP; ++e) { ex[e] = __expf(s[e] - m); sum += ex[e]; }
      float inv = 1.f / sum;
#pragma unroll
      for (int e = 0; e < EEXP; ++e) {
        float p = ex[e] * inv;
        impAcc[e] += p;
        entAcc += p * __logf(fmaxf(p, 1e-9f));
      }
      // top-2, strict > keeps lowest index on ties (matches jax.lax.top_k)
      int e0 = 0;
#pragma unroll
      for (int e = 1; e < EEXP; ++e) if (s[e] > s[e0]) e0 = e;
      int e1 = (e0 == 0) ? 1 : 0;
#pragma unroll
      for (int e = 0; e < EEXP; ++e) if (e != e0 && s[e] > s[e1]) e1 = e;
      float tt = __expf(s[e1] - s[e0]);
      float p0 = 1.f / (1.f + tt);
      float p1 = tt / (1.f + tt);
      int pos0 = atomicAdd(&sCnt[e0], 1);
      sSlot[e0][pos0] = t * 2;     sWt[e0][pos0] = p0;
      int pos1 = atomicAdd(&sCnt[e1], 1);
      sSlot[e1][pos1] = t * 2 + 1; sWt[e1][pos1] = p1;
    }
  }
  if (lane == 0) {
#pragma unroll
    for (int e = 0; e < EEXP; ++e) atomicAdd(&sImp[e], impAcc[e]);
    atomicAdd(&sEnt, entAcc);
  }
  __syncthreads();
  if (tid < EEXP) {
    sBase[tid] = atomicAdd(&cnt[tid << 4], sCnt[tid]);   // padded line per expert
    atomicAdd(&imp[tid << 4], sImp[tid]);
  }
  if (tid == EEXP) atomicAdd(entacc, sEnt);
  __syncthreads();
#pragma unroll
  for (int e = 0; e < EEXP; ++e) {
    int n = sCnt[e], b = sBase[e];
    for (int i = tid; i < n; i += 256) {
      slots[e * CAP + b + i] = sSlot[e][i];
      wlist[e * CAP + b + i] = sWt[e][i];
    }
  }
}

// ---------------- finalize aux losses ----------------
__global__ void finalize_kernel(const int* __restrict__ cnt, const float* __restrict__ imp,
                                const float* __restrict__ ent, float* __restrict__ outl) {
  if (threadIdx.x == 0 && blockIdx.x == 0) {
    float lb = 0.f;
    for (int e = 0; e < EEXP; ++e)
      lb += (imp[e << 4] / (float)TTOK) * ((float)cnt[e << 4] / (float)(TTOK * 2));
    lb *= (float)EEXP;
    float el = ent[0] / (float)TTOK;
    outl[0] = lb;
    outl[1] = el;
    outl[2] = 0.01f * lb;   // + 0.0f * ent
  }
}

// ---------------- fused GEMM1+GEMM2+SiLU -> Hid (bf16) + W3 cvt plane ----------------
// GEMM body r13-exact (measured ~90us). New: blockIdx.z == EEXP plane does the
// W3 fp32->bf16 conversion (pure BW, hides under the GEMM's idle memory pipe;
// W3b consumed only by the NEXT dispatch, so stream order covers the dep).
__global__ __launch_bounds__(256, 2) void gemm12_kernel(
    const unsigned short* __restrict__ xb,   // [T][D]
    const unsigned short* __restrict__ W1b,  // [E][H][D]
    const unsigned short* __restrict__ W2b,  // [E][H][D]
    const float* __restrict__ W3,            // [E][D][H] fp32 in
    unsigned short* __restrict__ W3b,        // [E][D][H] bf16 out
    unsigned short* __restrict__ Hid,        // [2T][H]
    const int* __restrict__ cnt,             // padded: cnt[e*16]
    const int* __restrict__ slots)           // [E][CAP]
{
  if (blockIdx.z == EEXP) {
    // -------- W3 conversion plane (512 blocks, grid-stride) --------
    const int b = blockIdx.y * gridDim.x + blockIdx.x;
    const int nb = gridDim.x * gridDim.y;
    cvt_stride((const float4*)W3, (ushort4*)W3b,
               b * 256 + threadIdx.x, nb * 256, EEXP * DDIM * HDIM / 4);
    return;
  }

  const int e = blockIdx.z;
  const int ne = cnt[e << 4];
  const int m0 = blockIdx.y * 128;
  if (m0 >= ne) return;
  const int n0 = blockIdx.x * 128;

  __shared__ unsigned short sA[128 * 64];
  __shared__ unsigned short sB1[128 * 64];
  __shared__ unsigned short sB2[128 * 64];

  const int tid = threadIdx.x;
  const int lane = tid & 63;
  const int wv = tid >> 6;
  const int wr = wv >> 1, wc = wv & 1;
  const int* eslots = slots + e * CAP;

  // stage source column: slot (tid&7) XOR row&7 ((tid>>3)&7), 16B granules
  const int cole = ((tid & 7) ^ ((tid >> 3) & 7)) * 8;
  const unsigned short* gA[4];
  const unsigned short* gB1[4];
  const unsigned short* gB2[4];
  char* lA[4]; char* lB1[4]; char* lB2[4];
  const size_t wbase = (size_t)e * HDIM * DDIM;
#pragma unroll
  for (int i = 0; i < 4; ++i) {
    int p = m0 + (tid >> 3) + i * 32;
    int sl = eslots[(p < ne) ? p : 0];
    gA[i]  = xb + (size_t)(sl >> 1) * DDIM + cole;
    int r = i * 32 + (tid >> 3);
    gB1[i] = W1b + wbase + (size_t)(n0 + r) * DDIM + cole;
    gB2[i] = W2b + wbase + (size_t)(n0 + r) * DDIM + cole;
    lA[i]  = (char*)sA  + (size_t)(i * 256 + (tid & ~63)) * 16;
    lB1[i] = (char*)sB1 + (size_t)(i * 256 + (tid & ~63)) * 16;
    lB2[i] = (char*)sB2 + (size_t)(i * 256 + (tid & ~63)) * 16;
  }

  f32x4 acc1[4][4], acc2[4][4];
#pragma unroll
  for (int m = 0; m < 4; ++m)
#pragma unroll
    for (int n = 0; n < 4; ++n) {
      acc1[m][n] = f32x4{0.f, 0.f, 0.f, 0.f};
      acc2[m][n] = f32x4{0.f, 0.f, 0.f, 0.f};
    }

  const int fr = lane & 15;
  const int g = lane >> 4;
  const int frx = fr & 7;            // read-side XOR key (row&7 == fr&7)

  for (int kt = 0; kt < DDIM / 64; ++kt) {
#pragma unroll
    for (int i = 0; i < 4; ++i) {
      gl16(gA[i],  lA[i]);  gA[i]  += 64;
      gl16(gB1[i], lB1[i]); gB1[i] += 64;
      gl16(gB2[i], lB2[i]); gB2[i] += 64;
    }
    __syncthreads();
#pragma unroll
    for (int kk = 0; kk < 2; ++kk) {
      bfrag a[4], b1[4], b2[4];
      const int so = ((kk * 4 + g) ^ frx) * 8;   // swizzled slot offset (elems)
#pragma unroll
      for (int m = 0; m < 4; ++m)
        a[m] = *(const bfrag*)&sA[(wr * 64 + m * 16 + fr) * 64 + so];
#pragma unroll
      for (int n = 0; n < 4; ++n) {
        b1[n] = *(const bfrag*)&sB1[(wc * 64 + n * 16 + fr) * 64 + so];
        b2[n] = *(const bfrag*)&sB2[(wc * 64 + n * 16 + fr) * 64 + so];
      }
#pragma unroll
      for (int m = 0; m < 4; ++m)
#pragma unroll
        for (int n = 0; n < 4; ++n) {
          acc1[m][n] = __builtin_amdgcn_mfma_f32_16x16x32_bf16(a[m], b1[n], acc1[m][n], 0, 0, 0);
          acc2[m][n] = __builtin_amdgcn_mfma_f32_16x16x32_bf16(a[m], b2[n], acc2[m][n], 0, 0, 0);
        }
    }
    __syncthreads();
  }

  const int rb = g * 4;
#pragma unroll
  for (int m = 0; m < 4; ++m) {
#pragma unroll
    for (int j = 0; j < 4; ++j) {
      int p = m0 + wr * 64 + m * 16 + rb + j;
      if (p >= ne) continue;
      size_t srow = (size_t)eslots[p] * HDIM;
#pragma unroll
      for (int n = 0; n < 4; ++n) {
        int col = n0 + wc * 64 + n * 16 + fr;
        float c1 = acc1[m][n][j], c2 = acc2[m][n][j];
        float h = c1 / (1.f + __expf(-c1)) * c2;
        Hid[srow + col] = f2bf(h);
      }
    }
  }
}

// ---------------- GEMM3: y += w * (Hid @ W3^T) ----------------
// r13-exact (measured ~95us): bf16 W3, 128x128, BK=64, K-split x2, 32 KiB LDS.
__global__ __launch_bounds__(256, 2) void gemm3_kernel(
    const unsigned short* __restrict__ Hid,  // [2T][H]
    const unsigned short* __restrict__ W3b,  // [E][D][H]
    float* __restrict__ y,                   // [T][D]
    const int* __restrict__ cnt,             // padded: cnt[e*16]
    const int* __restrict__ slots,
    const float* __restrict__ wlist)
{
  const int e  = blockIdx.z >> 1;
  const int ks = blockIdx.z & 1;           // K half: cols ks*1024 .. +1023
  const int ne = cnt[e << 4];
  const int m0 = blockIdx.y * 128;
  if (m0 >= ne) return;
  const int n0 = blockIdx.x * 128;

  __shared__ unsigned short sA[128 * 64];   // 16 KiB
  __shared__ unsigned short sB[128 * 64];   // 16 KiB

  const int tid = threadIdx.x;
  const int lane = tid & 63;
  const int wv = tid >> 6;
  const int wr = wv >> 1, wc = wv & 1;     // 2M x 2N waves
  const int* eslots = slots + e * CAP;

  const int cole = ((tid & 7) ^ ((tid >> 3) & 7)) * 8;  // pre-swizzled src slot
  const unsigned short* gA[4];
  const unsigned short* gB[4];
  char* lA[4]; char* lB[4];
  const size_t wbase = (size_t)e * DDIM * HDIM;
#pragma unroll
  for (int i = 0; i < 4; ++i) {
    int p = m0 + (tid >> 3) + i * 32;
    int sl = eslots[(p < ne) ? p : 0];
    gA[i] = Hid + (size_t)sl * HDIM + ks * 1024 + cole;
    int r = n0 + (tid >> 3) + i * 32;
    gB[i] = W3b + wbase + (size_t)r * HDIM + ks * 1024 + cole;
    lA[i] = (char*)sA + (size_t)(i * 256 + (tid & ~63)) * 16;
    lB[i] = (char*)sB + (size_t)(i * 256 + (tid & ~63)) * 16;
  }

  f32x4 acc[4][4];
#pragma unroll
  for (int m = 0; m < 4; ++m)
#pragma unroll
    for (int n = 0; n < 4; ++n) acc[m][n] = f32x4{0.f, 0.f, 0.f, 0.f};

  const int fr = lane & 15;
  const int g = lane >> 4;
  const int frx = fr & 7;

  for (int kt = 0; kt < 16; ++kt) {        // K=1024 per split, BK=64
#pragma unroll
    for (int i = 0; i < 4; ++i) {
      gl16(gA[i], lA[i]); gA[i] += 64;
      gl16(gB[i], lB[i]); gB[i] += 64;
    }
    __syncthreads();
#pragma unroll
    for (int kk = 0; kk < 2; ++kk) {
      bfrag a[4], b[4];
      const int so = ((kk * 4 + g) ^ frx) * 8;
#pragma unroll
      for (int m = 0; m < 4; ++m)
        a[m] = *(const bfrag*)&sA[(wr * 64 + m * 16 + fr) * 64 + so];
#pragma unroll
      for (int n = 0; n < 4; ++n)
        b[n] = *(const bfrag*)&sB[(wc * 64 + n * 16 + fr) * 64 + so];
#pragma unroll
      for (int m = 0; m < 4; ++m)
#pragma unroll
        for (int n = 0; n < 4; ++n)
          acc[m][n] = __builtin_amdgcn_mfma_f32_16x16x32_bf16(a[m], b[n], acc[m][n], 0, 0, 0);
    }
    __syncthreads();
  }

  const int rb = g * 4;
#pragma unroll
  for (int m = 0; m < 4; ++m) {
#pragma unroll
    for (int j = 0; j < 4; ++j) {
      int p = m0 + wr * 64 + m * 16 + rb + j;
      if (p >= ne) continue;
      int sl = eslots[p];
      float w = wlist[e * CAP + p];
      float* yrow = y + (size_t)(sl >> 1) * DDIM;
#pragma unroll
      for (int n = 0; n < 4; ++n) {
        int col = n0 + wc * 64 + n * 16 + fr;
        unsafeAtomicAdd(&yrow[col], acc[m][n][j] * w);
      }
    }
  }
}

// ---------------- launcher ----------------
extern "C" void kernel_launch(void* const* d_in, const int* in_sizes, int n_in,
                              void* d_out, int out_size, void* d_ws, size_t ws_size,
                              hipStream_t stream) {
  const float* x  = (const float*)d_in[0];
  const float* Wg = (const float*)d_in[1];
  const float* W1 = (const float*)d_in[2];
  const float* W2 = (const float*)d_in[3];
  const float* W3 = (const float*)d_in[4];
  float* y    = (float*)d_out;
  float* outl = y + (size_t)TTOK * DDIM;

  char* ws = (char*)d_ws;
  size_t off = 0;
  auto alloc = [&](size_t bytes) {
    char* p = ws + off;
    off += (bytes + 255) & ~(size_t)255;
    return p;
  };
  unsigned short* xb  = (unsigned short*)alloc((size_t)TTOK * DDIM * 2);
  unsigned short* W1b = (unsigned short*)alloc((size_t)EEXP * HDIM * DDIM * 2);
  unsigned short* W2b = (unsigned short*)alloc((size_t)EEXP * HDIM * DDIM * 2);
  unsigned short* W3b = (unsigned short*)alloc((size_t)EEXP * DDIM * HDIM * 2);
  unsigned short* Hid = (unsigned short*)alloc((size_t)TTOK * 2 * HDIM * 2);
  int*   slots = (int*)alloc(EEXP * CAP * 4);
  float* wlist = (float*)alloc(EEXP * CAP * 4);
  char* hdr = alloc(1536);                 // padded: cnt 512B | imp 512B | ent
  int*   cnt = (int*)hdr;                  // cnt[e*16]
  float* imp = (float*)(hdr + 512);        // imp[e*16]
  float* ent = (float*)(hdr + 1024);
  if (ws_size < off) return;  // workspace too small — bail cleanly (143 MB < 170 MB proven)

  hipMemsetAsync(d_out, 0, (size_t)TTOK * DDIM * sizeof(float), stream);
  hipMemsetAsync(hdr, 0, 1536, stream);

  // gating + x-cvt + W1/W2-cvt in ONE dispatch (disjoint planes)
  prep_kernel<<<GATB + CVTB, 256, 0, stream>>>(
      x, Wg, xb, W1, W2, W1b, W2b, cnt, imp, ent, slots, wlist);
  finalize_kernel<<<1, 64, 0, stream>>>(cnt, imp, ent, outl);

  // gemm12 + W3-cvt plane (z == EEXP); W3b consumed by the next dispatch
  gemm12_kernel<<<dim3(HDIM / 128, CAP / 128, EEXP + 1), 256, 0, stream>>>(
      xb, W1b, W2b, W3, W3b, Hid, cnt, slots);

  gemm3_kernel<<<dim3(DDIM / 128, CAP / 128, EEXP * 2), 256, 0, stream>>>(
      Hid, W3b, y, cnt, slots, wlist);
}